// Round 1
// baseline (121.099 us; speedup 1.0000x reference)
//
#include <hip/hip_runtime.h>
#include <hip/hip_cooperative_groups.h>
#include <cmath>

namespace cg = cooperative_groups;

// NALU forward: B=8192, D=U=128.
// out = g1*a1 + (1-g1)*parity*exp(min(mlog,20)+slog)
//   a1   = x @ w1
//   mlog = log(max(|x|,1e-7)) @ w2
//   slog = (x<0) @ log|1-2*|w2^T||   (sign path in log space)
//   cnt  = (x<0) @ [1-2*|w2^T| < 0]  (parity of negative factors)
// Single cooperative kernel: wave 0 of each block computes a 64-element slice
// of the derived weights (prep) overlapped with x-staging; grid.sync();
// then the 4-chain MFMA body. Saves the separate prep dispatch + node gap.

typedef __bf16  bf16x8 __attribute__((ext_vector_type(8)));
typedef float   f32x4  __attribute__((ext_vector_type(4)));

__device__ __forceinline__ unsigned short f2bf(float f) {
    union { float f; unsigned int u; } v; v.f = f;
    unsigned int u = v.u;
    unsigned int r = (u + 0x7FFFu + ((u >> 16) & 1u)) >> 16;   // RNE
    return (unsigned short)r;
}

__device__ __forceinline__ unsigned int pck(unsigned short a, unsigned short b) {
    return (unsigned int)a | ((unsigned int)b << 16);
}

__device__ __forceinline__ float fast_sig(float v) {
    return 1.0f / (1.0f + __expf(-v));          // v_exp_f32 path
}
__device__ __forceinline__ float fast_tanh(float v) {
    return 1.0f - 2.0f / (1.0f + __expf(2.0f * v));
}

// MFMA B-fragment linear offset for value Bmat[k][n]:
//   lane = quad*16 + (n&15), quad=(k>>3)&3; [nblk(8)][kstep(4)][lane(64)][j(8)]
__device__ __forceinline__ int fragaddr(int n, int k) {
    int nblk = n >> 4, l16 = n & 15, kstep = k >> 5, quad = (k >> 3) & 3, j = k & 7;
    return (((nblk * 4 + kstep) * 64 + quad * 16 + l16) * 8) + j;
}

__global__ __launch_bounds__(256, 1)
void nalu_fused(const float* __restrict__ x,
                const float* __restrict__ w_hat,
                const float* __restrict__ m_hat,
                const float* __restrict__ whp,
                const float* __restrict__ mhp,
                const float* __restrict__ g,
                unsigned short* __restrict__ Bsw,
                float* __restrict__ out) {
    __shared__ __align__(16) unsigned short As[3][32][136];

    const int t    = threadIdx.x;
    const int wave = t >> 6;
    const int lane = t & 63;
    const int quad = lane >> 4;
    const int l16  = lane & 15;
    const int rowblk = blockIdx.x * 32;

    // --- Issue x loads first (HBM latency hides under prep compute) ---
    const float4* xv = reinterpret_cast<const float4*>(x + rowblk * 128);
    float4 vbuf[4];
    #pragma unroll
    for (int it = 0; it < 4; ++it) vbuf[it] = xv[t + it * 256];

    // --- Prep slice: wave 0 only (uniform branch, no divergence).
    // Thread handles element e=(d,u); S/neg for the TRANSPOSED slot are
    // functions of w2[d][u], so 4 coalesced loads cover all 4 matrices. ---
    if (t < 64) {
        int e  = blockIdx.x * 64 + t;       // 0..16383
        int d  = e >> 7;                    // reduction index
        int u  = e & 127;                   // output column (fast -> coalesced)
        int dk = d * 128 + u;

        float w1v = fast_tanh(w_hat[dk]) * fast_sig(m_hat[dk]);
        float w2v = fast_tanh(whp[dk])   * fast_sig(mhp[dk]);
        float a   = fabsf(w2v);
        float f   = 1.0f - 2.0f * a;
        float Sv  = fmaxf(__logf(fmaxf(fabsf(f), 1e-38f)), -80.0f);
        float ngv = (f < 0.0f) ? 1.0f : 0.0f;

        const int MS = 16384;
        Bsw[fragaddr(u, d)]          = f2bf(w1v);   // w1[k=d][n=u]
        Bsw[fragaddr(u, d) + MS]     = f2bf(w2v);   // w2[k=d][n=u]
        Bsw[fragaddr(d, u) + 2 * MS] = f2bf(Sv);    // S[k=u][n=d] = f(w2[d][u])
        Bsw[fragaddr(d, u) + 3 * MS] = f2bf(ngv);   // neg[k=u][n=d]
    }

    // --- Stage A matrices (x, log|x|, x<0) into LDS as bf16 ---
    #pragma unroll
    for (int it = 0; it < 4; ++it) {
        int idx  = t + it * 256;            // 32 rows x 32 float4
        int row  = idx >> 5;
        int col4 = idx & 31;
        float4 v = vbuf[it];
        float vv[4] = {v.x, v.y, v.z, v.w};
        unsigned short sx[4], sl[4], sn[4];
        #pragma unroll
        for (int j = 0; j < 4; ++j) {
            float f = vv[j];
            sx[j] = f2bf(f);
            sl[j] = f2bf(__logf(fmaxf(fabsf(f), 1e-7f)));
            sn[j] = (f < 0.0f) ? 0x3F80u : 0u;   // bf16 1.0 / 0.0
        }
        uint2 px = {pck(sx[0], sx[1]), pck(sx[2], sx[3])};
        uint2 pl = {pck(sl[0], sl[1]), pck(sl[2], sl[3])};
        uint2 pn = {pck(sn[0], sn[1]), pck(sn[2], sn[3])};
        *reinterpret_cast<uint2*>(&As[0][row][col4 * 4]) = px;
        *reinterpret_cast<uint2*>(&As[1][row][col4 * 4]) = pl;
        *reinterpret_cast<uint2*>(&As[2][row][col4 * 4]) = pn;
    }
    __syncthreads();

    // --- Make Bsw stores visible device-wide, then grid barrier ---
    __threadfence();
    cg::this_grid().sync();

    // --- B-fragment loads (L2-hot, dwordx4) ---
    bf16x8 Bf[4][2][4];   // [mat][nsub][kstep]
    const bf16x8* Bp = reinterpret_cast<const bf16x8*>(Bsw);
    #pragma unroll
    for (int mat = 0; mat < 4; ++mat)
        #pragma unroll
        for (int ns = 0; ns < 2; ++ns)
            #pragma unroll
            for (int ks = 0; ks < 4; ++ks) {
                int nblk = wave * 2 + ns;
                Bf[mat][ns][ks] = Bp[((mat * 8 + nblk) * 4 + ks) * 64 + lane];
            }

    // --- Accumulators: 4 chains x 2 msub x 2 nsub ---
    f32x4 accA[2][2], accM[2][2], accS[2][2], accC[2][2];
    #pragma unroll
    for (int ms = 0; ms < 2; ++ms)
        #pragma unroll
        for (int ns = 0; ns < 2; ++ns) {
            f32x4 z = {0.0f, 0.0f, 0.0f, 0.0f};
            accA[ms][ns] = z; accM[ms][ns] = z; accS[ms][ns] = z; accC[ms][ns] = z;
        }

    // --- K loop: 4 ksteps of 32, fully unrolled ---
    #pragma unroll
    for (int ks = 0; ks < 4; ++ks) {
        bf16x8 Ax[2], Al[2], An[2];
        #pragma unroll
        for (int ms = 0; ms < 2; ++ms) {
            int m = ms * 16 + l16;
            int k = ks * 32 + quad * 8;
            Ax[ms] = *reinterpret_cast<const bf16x8*>(&As[0][m][k]);
            Al[ms] = *reinterpret_cast<const bf16x8*>(&As[1][m][k]);
            An[ms] = *reinterpret_cast<const bf16x8*>(&As[2][m][k]);
        }
        #pragma unroll
        for (int ms = 0; ms < 2; ++ms)
            #pragma unroll
            for (int ns = 0; ns < 2; ++ns) {
                accA[ms][ns] = __builtin_amdgcn_mfma_f32_16x16x32_bf16(Ax[ms], Bf[0][ns][ks], accA[ms][ns], 0, 0, 0);
                accM[ms][ns] = __builtin_amdgcn_mfma_f32_16x16x32_bf16(Al[ms], Bf[1][ns][ks], accM[ms][ns], 0, 0, 0);
                accS[ms][ns] = __builtin_amdgcn_mfma_f32_16x16x32_bf16(An[ms], Bf[2][ns][ks], accS[ms][ns], 0, 0, 0);
                accC[ms][ns] = __builtin_amdgcn_mfma_f32_16x16x32_bf16(An[ms], Bf[3][ns][ks], accC[ms][ns], 0, 0, 0);
            }
    }

    // --- Epilogue: C/D layout col=lane&15, row=quad*4+reg ---
    #pragma unroll
    for (int ns = 0; ns < 2; ++ns) {
        int u = wave * 32 + ns * 16 + l16;
        float g1 = fast_sig(g[u]);
        float om = 1.0f - g1;
        #pragma unroll
        for (int ms = 0; ms < 2; ++ms) {
            int rbase = rowblk + ms * 16 + quad * 4;
            #pragma unroll
            for (int r = 0; r < 4; ++r) {
                float a1 = accA[ms][ns][r];
                float ml = accM[ms][ns][r];
                float sl = accS[ms][ns][r];
                float cn = accC[ms][ns][r];   // exact integer count
                float par = 1.0f - 2.0f * (cn - 2.0f * floorf(cn * 0.5f));
                float mterm = par * __expf(fminf(ml, 20.0f) + sl);
                out[(rbase + r) * 128 + u] = g1 * a1 + om * mterm;
            }
        }
    }
}

extern "C" void kernel_launch(void* const* d_in, const int* in_sizes, int n_in,
                              void* d_out, int out_size, void* d_ws, size_t ws_size,
                              hipStream_t stream) {
    const float* x     = (const float*)d_in[0];
    const float* w_hat = (const float*)d_in[1];
    const float* m_hat = (const float*)d_in[2];
    const float* whp   = (const float*)d_in[3];
    const float* mhp   = (const float*)d_in[4];
    const float* g     = (const float*)d_in[5];
    unsigned short* Bsw = (unsigned short*)d_ws;   // 4*16384*2 = 128 KiB
    float* outp = (float*)d_out;

    void* args[] = {(void*)&x, (void*)&w_hat, (void*)&m_hat, (void*)&whp,
                    (void*)&mhp, (void*)&g, (void*)&Bsw, (void*)&outp};
    hipLaunchCooperativeKernel((const void*)nalu_fused, dim3(256), dim3(256),
                               args, 0, stream);
}

// Round 2
// 75.125 us; speedup vs baseline: 1.6120x; 1.6120x over previous
//
#include <hip/hip_runtime.h>
#include <cmath>

// NALU forward: B=8192, D=U=128, single sync-free fused kernel.
// out = g1*a1 + (1-g1)*parity*exp(min(mlog,20)+slog)
//   a1   = x @ w1
//   mlog = log(max(|x|,1e-7)) @ w2
//   slog = (x<0) @ log|1-2*|w2^T||   (sign path, log space)
//   cnt  = (x<0) @ [1-2*|w2^T| < 0]  (parity of negative factors)
// Decomposition: 256 blocks = 64 rowblocks(128 rows) x 4 colblocks(32 cols).
// Each block computes its own 32-column slice of the 4 derived B-matrices
// straight into LDS fragment layout (no prep kernel, no workspace, no grid
// sync); x HBM latency hides under the weight transcendentals.

typedef __bf16  bf16x8 __attribute__((ext_vector_type(8)));
typedef float   f32x4  __attribute__((ext_vector_type(4)));

__device__ __forceinline__ unsigned short f2bf(float f) {
    union { float f; unsigned int u; } v; v.f = f;
    unsigned int u = v.u;
    unsigned int r = (u + 0x7FFFu + ((u >> 16) & 1u)) >> 16;   // RNE
    return (unsigned short)r;
}
__device__ __forceinline__ unsigned int pck(unsigned short a, unsigned short b) {
    return (unsigned int)a | ((unsigned int)b << 16);
}
__device__ __forceinline__ float fast_sig(float v) {
    return 1.0f / (1.0f + __expf(-v));
}
__device__ __forceinline__ float fast_tanh(float v) {
    return 1.0f - 2.0f / (1.0f + __expf(2.0f * v));
}

// Element offset of B[k][n_local] within one 4096-element B-matrix, in MFMA
// B-fragment order: [nblk(2)][kstep(4)][lane=quad*16+l16][j(8)],
// lane: quad=(k>>3)&3, l16=n&15; j=k&7.
__device__ __forceinline__ int fragofs(int n, int k) {
    return ((n >> 4) * 4 + (k >> 5)) * 512 + ((k >> 3) & 3) * 128 + (n & 15) * 8 + (k & 7);
}

__global__ __launch_bounds__(256, 1)
void nalu_fused(const float* __restrict__ x,
                const float* __restrict__ w_hat,
                const float* __restrict__ m_hat,
                const float* __restrict__ whp,
                const float* __restrict__ mhp,
                const float* __restrict__ g,
                float* __restrict__ out) {
    __shared__ __align__(16) unsigned short As[3][128][136];   // 102 KB
    __shared__ __align__(16) unsigned short Bs[4 * 4096];      // 32 KB frag-order

    const int t    = threadIdx.x;
    const int wave = t >> 6;
    const int lane = t & 63;
    const int quad = lane >> 4;
    const int l16  = lane & 15;
    const int rowblk = (blockIdx.x & 63) * 128;   // row-sharing blocks -> same XCD
    const int c0     = (blockIdx.x >> 6) * 32;    // column slice

    // --- Issue all x loads first; HBM latency hides under weight compute ---
    const float4* xv = reinterpret_cast<const float4*>(x + rowblk * 128);
    float4 vbuf[16];
    #pragma unroll
    for (int it = 0; it < 16; ++it) vbuf[it] = xv[t + it * 256];

    // --- B mats 0,1: w1[k][n], w2[k][n] from row-slices of [D,U] arrays ---
    #pragma unroll
    for (int i = 0; i < 4; ++i) {
        int e  = t + i * 256;        // (k 0..127) x (n4 0..7)
        int k  = e >> 3;
        int n4 = (e & 7) * 4;
        int gi = k * 128 + c0 + n4;  // 16B-aligned, coalesced across lanes
        float4 wv = *reinterpret_cast<const float4*>(&w_hat[gi]);
        float4 mv = *reinterpret_cast<const float4*>(&m_hat[gi]);
        float4 pv = *reinterpret_cast<const float4*>(&whp[gi]);
        float4 qv = *reinterpret_cast<const float4*>(&mhp[gi]);
        float wa[4] = {wv.x, wv.y, wv.z, wv.w};
        float ma[4] = {mv.x, mv.y, mv.z, mv.w};
        float pa[4] = {pv.x, pv.y, pv.z, pv.w};
        float qa[4] = {qv.x, qv.y, qv.z, qv.w};
        #pragma unroll
        for (int j = 0; j < 4; ++j) {
            int fo = fragofs(n4 + j, k);
            Bs[fo]        = f2bf(fast_tanh(wa[j]) * fast_sig(ma[j]));
            Bs[fo + 4096] = f2bf(fast_tanh(pa[j]) * fast_sig(qa[j]));
        }
    }

    // --- B mats 2,3: S[k][n]=log|1-2|w2[n][k]||, neg[k][n]; n-rows of w2 are
    //     coalesced row reads; 8 consecutive k -> single b128 LDS store ---
    #pragma unroll
    for (int i = 0; i < 2; ++i) {
        int e  = t + i * 256;        // (nn 0..31) x (k-octet 0..15)
        int nn = e >> 4;
        int ko = e & 15;
        int gb = (c0 + nn) * 128 + ko * 8;
        float4 p0 = *reinterpret_cast<const float4*>(&whp[gb]);
        float4 p1 = *reinterpret_cast<const float4*>(&whp[gb + 4]);
        float4 q0 = *reinterpret_cast<const float4*>(&mhp[gb]);
        float4 q1 = *reinterpret_cast<const float4*>(&mhp[gb + 4]);
        float pa[8] = {p0.x, p0.y, p0.z, p0.w, p1.x, p1.y, p1.z, p1.w};
        float qa[8] = {q0.x, q0.y, q0.z, q0.w, q1.x, q1.y, q1.z, q1.w};
        unsigned int sv[4], nv[4];
        #pragma unroll
        for (int jj = 0; jj < 4; ++jj) {
            unsigned short s2[2], n2[2];
            #pragma unroll
            for (int h = 0; h < 2; ++h) {
                float w2v = fast_tanh(pa[jj * 2 + h]) * fast_sig(qa[jj * 2 + h]);
                float f   = 1.0f - 2.0f * fabsf(w2v);
                s2[h] = f2bf(fmaxf(__logf(fmaxf(fabsf(f), 1e-38f)), -80.0f));
                n2[h] = (f < 0.0f) ? (unsigned short)0x3F80u : (unsigned short)0u;
            }
            sv[jj] = pck(s2[0], s2[1]);
            nv[jj] = pck(n2[0], n2[1]);
        }
        int fo = fragofs(nn, ko * 8);   // j=0..7 contiguous, 16B aligned
        *reinterpret_cast<uint4*>(&Bs[fo + 2 * 4096]) = make_uint4(sv[0], sv[1], sv[2], sv[3]);
        *reinterpret_cast<uint4*>(&Bs[fo + 3 * 4096]) = make_uint4(nv[0], nv[1], nv[2], nv[3]);
    }

    // --- Stage A matrices (x, log|x|, x<0) into LDS as bf16 ---
    #pragma unroll
    for (int it = 0; it < 16; ++it) {
        int idx  = t + it * 256;     // 128 rows x 32 float4
        int row  = idx >> 5;
        int col4 = idx & 31;
        float4 v = vbuf[it];
        float vv[4] = {v.x, v.y, v.z, v.w};
        unsigned short sx[4], sl[4], sn[4];
        #pragma unroll
        for (int j = 0; j < 4; ++j) {
            float f = vv[j];
            sx[j] = f2bf(f);
            sl[j] = f2bf(__logf(fmaxf(fabsf(f), 1e-7f)));
            sn[j] = (f < 0.0f) ? (unsigned short)0x3F80u : (unsigned short)0u;
        }
        uint2 px = {pck(sx[0], sx[1]), pck(sx[2], sx[3])};
        uint2 pl = {pck(sl[0], sl[1]), pck(sl[2], sl[3])};
        uint2 pn = {pck(sn[0], sn[1]), pck(sn[2], sn[3])};
        *reinterpret_cast<uint2*>(&As[0][row][col4 * 4]) = px;
        *reinterpret_cast<uint2*>(&As[1][row][col4 * 4]) = pl;
        *reinterpret_cast<uint2*>(&As[2][row][col4 * 4]) = pn;
    }
    __syncthreads();

    // --- B-fragment loads from LDS (all waves share the block's 32 cols) ---
    bf16x8 Bf[4][2][4];   // [mat][nsub][kstep]
    const bf16x8* Bp = reinterpret_cast<const bf16x8*>(Bs);
    #pragma unroll
    for (int mat = 0; mat < 4; ++mat)
        #pragma unroll
        for (int ns = 0; ns < 2; ++ns)
            #pragma unroll
            for (int ks = 0; ks < 4; ++ks)
                Bf[mat][ns][ks] = Bp[mat * 512 + (ns * 4 + ks) * 64 + lane];

    // --- Accumulators: 4 chains x 2 msub x 2 nsub ---
    f32x4 accA[2][2], accM[2][2], accS[2][2], accC[2][2];
    #pragma unroll
    for (int ms = 0; ms < 2; ++ms)
        #pragma unroll
        for (int ns = 0; ns < 2; ++ns) {
            f32x4 z = {0.0f, 0.0f, 0.0f, 0.0f};
            accA[ms][ns] = z; accM[ms][ns] = z; accS[ms][ns] = z; accC[ms][ns] = z;
        }

    // --- K loop: wave owns rows [wave*32, +32); 4 ksteps of 32 ---
    #pragma unroll
    for (int ks = 0; ks < 4; ++ks) {
        bf16x8 Ax[2], Al[2], An[2];
        #pragma unroll
        for (int ms = 0; ms < 2; ++ms) {
            int m = wave * 32 + ms * 16 + l16;
            int k = ks * 32 + quad * 8;
            Ax[ms] = *reinterpret_cast<const bf16x8*>(&As[0][m][k]);
            Al[ms] = *reinterpret_cast<const bf16x8*>(&As[1][m][k]);
            An[ms] = *reinterpret_cast<const bf16x8*>(&As[2][m][k]);
        }
        #pragma unroll
        for (int ms = 0; ms < 2; ++ms)
            #pragma unroll
            for (int ns = 0; ns < 2; ++ns) {
                accA[ms][ns] = __builtin_amdgcn_mfma_f32_16x16x32_bf16(Ax[ms], Bf[0][ns][ks], accA[ms][ns], 0, 0, 0);
                accM[ms][ns] = __builtin_amdgcn_mfma_f32_16x16x32_bf16(Al[ms], Bf[1][ns][ks], accM[ms][ns], 0, 0, 0);
                accS[ms][ns] = __builtin_amdgcn_mfma_f32_16x16x32_bf16(An[ms], Bf[2][ns][ks], accS[ms][ns], 0, 0, 0);
                accC[ms][ns] = __builtin_amdgcn_mfma_f32_16x16x32_bf16(An[ms], Bf[3][ns][ks], accC[ms][ns], 0, 0, 0);
            }
    }

    // --- Epilogue: C/D layout col=lane&15, row=quad*4+reg ---
    #pragma unroll
    for (int ns = 0; ns < 2; ++ns) {
        int u = c0 + ns * 16 + l16;
        float g1 = fast_sig(g[u]);
        float om = 1.0f - g1;
        #pragma unroll
        for (int ms = 0; ms < 2; ++ms) {
            int rbase = rowblk + wave * 32 + ms * 16 + quad * 4;
            #pragma unroll
            for (int r = 0; r < 4; ++r) {
                float a1 = accA[ms][ns][r];
                float ml = accM[ms][ns][r];
                float sl = accS[ms][ns][r];
                float cn = accC[ms][ns][r];   // exact integer count
                float par = 1.0f - 2.0f * (cn - 2.0f * floorf(cn * 0.5f));
                float mterm = par * __expf(fminf(ml, 20.0f) + sl);
                out[(rbase + r) * 128 + u] = g1 * a1 + om * mterm;
            }
        }
    }
}

extern "C" void kernel_launch(void* const* d_in, const int* in_sizes, int n_in,
                              void* d_out, int out_size, void* d_ws, size_t ws_size,
                              hipStream_t stream) {
    const float* x     = (const float*)d_in[0];
    const float* w_hat = (const float*)d_in[1];
    const float* m_hat = (const float*)d_in[2];
    const float* whp   = (const float*)d_in[3];
    const float* mhp   = (const float*)d_in[4];
    const float* g     = (const float*)d_in[5];
    float* outp = (float*)d_out;
    (void)d_ws; (void)ws_size;

    nalu_fused<<<256, 256, 0, stream>>>(x, w_hat, m_hat, whp, mhp, g, outp);
}

// Round 4
// 69.538 us; speedup vs baseline: 1.7415x; 1.0803x over previous
//
#include <hip/hip_runtime.h>
#include <cmath>

// NALU forward: B=8192, D=U=128.
// out = g1*a1 + (1-g1)*parity*exp(min(mlog,20)+slog)
//   a1   = x @ w1
//   mlog = log(max(|x|,1e-7)) @ w2
//   slog = (x<0) @ log|1-2*|w2^T||   (sign path in log space)
//   cnt  = (x<0) @ [1-2*|w2^T| < 0]  (parity of negative factors)
// Structure: R0 two-kernel (empirically best: 71.8 vs 75.1 fused) with the
// two validated micro-opts: (a) prep uses 4 coalesced loads (S/neg derived
// from w2[d][u], no transposed re-read) + native transcendentals;
// (b) main uses native __logf/__expf (absmax bit-identical, validated R1/R2).

typedef __bf16  bf16x8 __attribute__((ext_vector_type(8)));
typedef float   f32x4  __attribute__((ext_vector_type(4)));

#define NROWS 8192
#define KDIM  128
#define UDIM  128

__device__ __forceinline__ unsigned short f2bf(float f) {
    union { float f; unsigned int u; } v; v.f = f;
    unsigned int u = v.u;
    unsigned int r = (u + 0x7FFFu + ((u >> 16) & 1u)) >> 16;   // RNE
    return (unsigned short)r;
}
__device__ __forceinline__ unsigned int pck(unsigned short a, unsigned short b) {
    return (unsigned int)a | ((unsigned int)b << 16);
}
__device__ __forceinline__ float fast_sig(float v) {
    return 1.0f / (1.0f + __expf(-v));          // v_exp_f32 path
}
__device__ __forceinline__ float fast_tanh(float v) {
    return 1.0f - 2.0f / (1.0f + __expf(2.0f * v));
}

// MFMA B-fragment linear offset for value Bmat[k][n] in the full 128-col
// matrix: [nblk(8)][kstep(4)][lane=quad*16+l16][j(8)], quad=(k>>3)&3.
__device__ __forceinline__ int fragaddr(int n, int k) {
    int nblk = n >> 4, l16 = n & 15, kstep = k >> 5, quad = (k >> 3) & 3, j = k & 7;
    return (((nblk * 4 + kstep) * 64 + quad * 16 + l16) * 8) + j;
}

// ---------------------------------------------------------------------------
// Prep: 4 derived weight matrices in bf16, MFMA B-fragment order.
// Thread handles element (d,u) with u fast-varying -> ALL 4 loads coalesced.
// S/neg for the transposed slot (k=u, n=d) are functions of w2[d][u], so no
// transposed re-read is needed (validated R1: absmax unchanged).
// ---------------------------------------------------------------------------
__global__ void nalu_prep(const float* __restrict__ w_hat,
                          const float* __restrict__ m_hat,
                          const float* __restrict__ whp,
                          const float* __restrict__ mhp,
                          unsigned short* __restrict__ Bsw) {
    int i = blockIdx.x * 256 + threadIdx.x;   // 0..16383
    int d = i >> 7;      // reduction index
    int u = i & 127;     // output column (fast -> coalesced)
    int dk = d * 128 + u;

    float w1v = fast_tanh(w_hat[dk]) * fast_sig(m_hat[dk]);
    float w2v = fast_tanh(whp[dk])   * fast_sig(mhp[dk]);
    float f   = 1.0f - 2.0f * fabsf(w2v);
    float Sv  = fmaxf(__logf(fmaxf(fabsf(f), 1e-38f)), -80.0f);
    float ngv = (f < 0.0f) ? 1.0f : 0.0f;

    const int MS = 16384;
    Bsw[fragaddr(u, d)]          = f2bf(w1v);   // w1[k=d][n=u]
    Bsw[fragaddr(u, d) + MS]     = f2bf(w2v);   // w2[k=d][n=u]
    Bsw[fragaddr(d, u) + 2 * MS] = f2bf(Sv);    // S[k=u][n=d] = f(w2[d][u])
    Bsw[fragaddr(d, u) + 3 * MS] = f2bf(ngv);   // neg[k=u][n=d]
}

// ---------------------------------------------------------------------------
// Main: 256 blocks x 256 threads. Block = 32 rows x 128 cols.
// Wave w: rows [blk*32, +32) (2 msub of 16), cols [w*32, +32) (2 nsub of 16).
// A staged in LDS as [mat][m 32][k 136] bf16 (pad keeps 16B align, 2-way banks).
// ---------------------------------------------------------------------------
__global__ __launch_bounds__(256, 1)
void nalu_main(const float* __restrict__ x,
               const unsigned short* __restrict__ Bsw,
               const float* __restrict__ g,
               float* __restrict__ out) {
    __shared__ __align__(16) unsigned short As[3][32][136];

    const int t    = threadIdx.x;
    const int wave = t >> 6;
    const int lane = t & 63;
    const int quad = lane >> 4;
    const int l16  = lane & 15;
    const int rowblk = blockIdx.x * 32;

    // --- Issue all B-fragment loads up front (coalesced dwordx4, L2-hot) ---
    bf16x8 Bf[4][2][4];   // [mat][nsub][kstep]
    const bf16x8* Bp = reinterpret_cast<const bf16x8*>(Bsw);
    #pragma unroll
    for (int mat = 0; mat < 4; ++mat)
        #pragma unroll
        for (int ns = 0; ns < 2; ++ns)
            #pragma unroll
            for (int ks = 0; ks < 4; ++ks) {
                int nblk = wave * 2 + ns;
                Bf[mat][ns][ks] = Bp[((mat * 8 + nblk) * 4 + ks) * 64 + lane];
            }

    // --- Stage A matrices (x, log|x|, x<0) into LDS as bf16 ---
    const float4* xv = reinterpret_cast<const float4*>(x + rowblk * 128);
    #pragma unroll
    for (int it = 0; it < 4; ++it) {
        int idx  = t + it * 256;      // 0..1023 = 32 rows x 32 float4
        int row  = idx >> 5;
        int col4 = idx & 31;
        float4 v = xv[idx];
        float vv[4] = {v.x, v.y, v.z, v.w};
        unsigned short sx[4], sl[4], sn[4];
        #pragma unroll
        for (int j = 0; j < 4; ++j) {
            float f = vv[j];
            sx[j] = f2bf(f);
            sl[j] = f2bf(__logf(fmaxf(fabsf(f), 1e-7f)));
            sn[j] = (f < 0.0f) ? (unsigned short)0x3F80u : (unsigned short)0u;
        }
        uint2 px = {pck(sx[0], sx[1]), pck(sx[2], sx[3])};
        uint2 pl = {pck(sl[0], sl[1]), pck(sl[2], sl[3])};
        uint2 pn = {pck(sn[0], sn[1]), pck(sn[2], sn[3])};
        *reinterpret_cast<uint2*>(&As[0][row][col4 * 4]) = px;
        *reinterpret_cast<uint2*>(&As[1][row][col4 * 4]) = pl;
        *reinterpret_cast<uint2*>(&As[2][row][col4 * 4]) = pn;
    }
    __syncthreads();

    // --- Accumulators: 4 chains x 2 msub x 2 nsub ---
    f32x4 accA[2][2], accM[2][2], accS[2][2], accC[2][2];
    #pragma unroll
    for (int ms = 0; ms < 2; ++ms)
        #pragma unroll
        for (int ns = 0; ns < 2; ++ns) {
            f32x4 z = {0.0f, 0.0f, 0.0f, 0.0f};
            accA[ms][ns] = z; accM[ms][ns] = z; accS[ms][ns] = z; accC[ms][ns] = z;
        }

    // --- K loop: 4 ksteps of 32, fully unrolled ---
    #pragma unroll
    for (int ks = 0; ks < 4; ++ks) {
        bf16x8 Ax[2], Al[2], An[2];
        #pragma unroll
        for (int ms = 0; ms < 2; ++ms) {
            int m = ms * 16 + l16;
            int k = ks * 32 + quad * 8;
            Ax[ms] = *reinterpret_cast<const bf16x8*>(&As[0][m][k]);
            Al[ms] = *reinterpret_cast<const bf16x8*>(&As[1][m][k]);
            An[ms] = *reinterpret_cast<const bf16x8*>(&As[2][m][k]);
        }
        #pragma unroll
        for (int ms = 0; ms < 2; ++ms)
            #pragma unroll
            for (int ns = 0; ns < 2; ++ns) {
                accA[ms][ns] = __builtin_amdgcn_mfma_f32_16x16x32_bf16(Ax[ms], Bf[0][ns][ks], accA[ms][ns], 0, 0, 0);
                accM[ms][ns] = __builtin_amdgcn_mfma_f32_16x16x32_bf16(Al[ms], Bf[1][ns][ks], accM[ms][ns], 0, 0, 0);
                accS[ms][ns] = __builtin_amdgcn_mfma_f32_16x16x32_bf16(An[ms], Bf[2][ns][ks], accS[ms][ns], 0, 0, 0);
                accC[ms][ns] = __builtin_amdgcn_mfma_f32_16x16x32_bf16(An[ms], Bf[3][ns][ks], accC[ms][ns], 0, 0, 0);
            }
    }

    // --- Epilogue: C/D layout col=lane&15, row=quad*4+reg ---
    #pragma unroll
    for (int ns = 0; ns < 2; ++ns) {
        int u = wave * 32 + ns * 16 + l16;
        float g1 = fast_sig(g[u]);
        float om = 1.0f - g1;
        #pragma unroll
        for (int ms = 0; ms < 2; ++ms) {
            int rbase = rowblk + ms * 16 + quad * 4;
            #pragma unroll
            for (int r = 0; r < 4; ++r) {
                float a1 = accA[ms][ns][r];
                float ml = accM[ms][ns][r];
                float sl = accS[ms][ns][r];
                float cn = accC[ms][ns][r];   // exact integer count
                float par = 1.0f - 2.0f * (cn - 2.0f * floorf(cn * 0.5f));
                float mterm = par * __expf(fminf(ml, 20.0f) + sl);
                out[(rbase + r) * 128 + u] = g1 * a1 + om * mterm;
            }
        }
    }
}

extern "C" void kernel_launch(void* const* d_in, const int* in_sizes, int n_in,
                              void* d_out, int out_size, void* d_ws, size_t ws_size,
                              hipStream_t stream) {
    const float* x     = (const float*)d_in[0];
    const float* w_hat = (const float*)d_in[1];
    const float* m_hat = (const float*)d_in[2];
    const float* whp   = (const float*)d_in[3];
    const float* mhp   = (const float*)d_in[4];
    const float* g     = (const float*)d_in[5];
    unsigned short* Bsw = (unsigned short*)d_ws;   // 4*16384*2 = 128 KiB
    float* outp = (float*)d_out;

    nalu_prep<<<64, 256, 0, stream>>>(w_hat, m_hat, whp, mhp, Bsw);
    nalu_main<<<256, 256, 0, stream>>>(x, Bsw, g, outp);
}